// Round 15
// baseline (118.404 us; speedup 1.0000x reference)
//
#include <hip/hip_runtime.h>
#include <hip/hip_bf16.h>
#include <cstdint>

// Problem dims (fixed by reference setup_inputs)
constexpr int Bn = 16;    // batch
constexpr int Sn = 1024;  // source length
constexpr int Tn = 512;   // query steps
constexpr int QD = 256;   // query vec size
constexpr int En = 512;   // src encoding size
constexpr int Hn = 4;     // heads
constexpr float SLOPE = 0.01f;   // jax.nn.leaky_relu default
constexpr float NEG_INF = -1e9f;
constexpr int Mn = Bn * Sn;      // 16384 rows of the projection GEMM

typedef _Float16 f16;
typedef f16 f16x4 __attribute__((ext_vector_type(4)));
typedef f16 f16x8 __attribute__((ext_vector_type(8)));
typedef float f32x4 __attribute__((ext_vector_type(4)));

// async global->LDS, 16B per lane; dest = wave-uniform base + lane*16
#define G2L(g, l) __builtin_amdgcn_global_load_lds(                      \
    (const __attribute__((address_space(1))) void*)(g),                  \
    (__attribute__((address_space(3))) void*)(l), 16, 0, 0)

#define VM4 asm volatile("s_waitcnt vmcnt(4)" ::: "memory")
#define VM0 asm volatile("s_waitcnt vmcnt(0)" ::: "memory")
#define LG0 asm volatile("s_waitcnt lgkmcnt(0)" ::: "memory")

// ---------------------------------------------------------------------------
// PREP: fused conv_b (blocks 0..127) + conv_q (128..2175) + detect (2176).
//   conv_a is GONE — gemm1 now stages A directly from f32 src.
// ---------------------------------------------------------------------------
__global__ __launch_bounds__(256) void prep_kernel(
    const float* __restrict__ W, const float* __restrict__ query,
    const unsigned char* __restrict__ mask_bytes,
    f16* __restrict__ Bht, f16* __restrict__ Blt,
    f16* __restrict__ Qh, f16* __restrict__ Ql,
    int* __restrict__ flag)
{
    __shared__ float T[64][65];
    __shared__ int cnt;
    const int bid = blockIdx.x;
    const int tid = threadIdx.x;

    if (bid < 128) {
        // ---- conv_b: W (512x1024) -> Bht/Blt (1024x512) transposed+split ----
        const int n0 = (bid & 15) * 64;
        const int k0 = (bid >> 4) * 64;
        #pragma unroll
        for (int p = 0; p < 4; ++p) {
            const int e = p * 256 + tid;
            const int r = e >> 4;
            const int c4 = e & 15;
            const float4 v = *(const float4*)(W + (size_t)(k0 + r) * (Hn * QD) + n0 + c4 * 4);
            T[r][c4 * 4 + 0] = v.x; T[r][c4 * 4 + 1] = v.y;
            T[r][c4 * 4 + 2] = v.z; T[r][c4 * 4 + 3] = v.w;
        }
        __syncthreads();
        #pragma unroll
        for (int p = 0; p < 4; ++p) {
            const int e = p * 256 + tid;
            const int r = e >> 4;
            const int c4 = e & 15;
            f16x4 hi, lo;
            #pragma unroll
            for (int j = 0; j < 4; ++j) {
                const float x = T[c4 * 4 + j][r];
                f16 h = (f16)x;
                hi[j] = h;
                lo[j] = (f16)(x - (float)h);
            }
            const size_t off = (size_t)(n0 + r) * En + k0 + c4 * 4;
            *(f16x4*)(Bht + off) = hi;
            *(f16x4*)(Blt + off) = lo;
        }
    } else if (bid < 2176) {
        // ---- conv_q: query (512,16,256) -> Qh/Ql (b,t,q) f16 split ----
        const int rloc = tid >> 6;
        const int lane = tid & 63;
        const int row = (bid - 128) * 4 + rloc;   // (t,b) pair, t-major
        const int t = row >> 4, b = row & 15;
        const float4 v = *(const float4*)(query + (size_t)row * QD + lane * 4);
        f16x4 hi, lo;
        const float xs[4] = {v.x, v.y, v.z, v.w};
        #pragma unroll
        for (int j = 0; j < 4; ++j) {
            f16 h = (f16)xs[j];
            hi[j] = h;
            lo[j] = (f16)(xs[j] - (float)h);
        }
        const size_t off = ((size_t)(b * Tn + t)) * QD + lane * 4;
        *(f16x4*)(Qh + off) = hi;
        *(f16x4*)(Ql + off) = lo;
    } else {
        // ---- detect mask dtype ----
        if (tid == 0) cnt = 0;
        __syncthreads();
        int local = 0;
        for (int p = tid; p < 4096; p += 256) {
            if ((p & 3) != 0 && mask_bytes[p] != 0) local++;
        }
        atomicAdd(&cnt, local);
        __syncthreads();
        if (tid == 0) flag[0] = (cnt == 0) ? 1 : 0;
    }
}

// ---------------------------------------------------------------------------
// K1: 128(rows) x 256(cols = 64q x 4heads) tile, BK=32, ring-3.
//   A is staged DIRECTLY from f32 src: lead-1 flat loads -> cvt hi/lo ->
//   ds_write (phase selector: t<16 hi, 16..31 lo, >=32 hi). B stays lead-2
//   G2L. End-of-phase vmcnt(4): A(t+1) returned + B(t+1) landed (issue order
//   A(t+1) then B(t+2) => only B(t+2)'s 4 outstanding). Tail VM0 at t=46.
//   Slot halves disjoint: A [0,4096), B [4096,12288). XOR placement matches
//   the frozen frag-read involution. XCD swizzle: same-A quads co-XCD.
// ---------------------------------------------------------------------------
__global__ __launch_bounds__(256) void gemm1_kernel(
    const float* __restrict__ src,
    const f16* __restrict__ Bht, const f16* __restrict__ Blt,
    const float* __restrict__ wcomb,
    f16* __restrict__ Ch, f16* __restrict__ Cl)
{
    __shared__ f16 lds_f[36864];   // 3 slots x 12288 f16 = 72 KB

    const int tid = threadIdx.x;
    const int l  = tid & 63;
    const int wv = tid >> 6;         // 0..3
    const int wm = wv >> 1;          // M half (64 rows)
    const int wn = wv & 1;           // q half (32 q)

    // XCD swizzle: 512 blocks, 8 XCDs, 64 per XCD; same-A quads co-XCD
    const int bid = blockIdx.x;
    const int swz = (bid & 7) * 64 + (bid >> 3);
    const int m0 = (swz >> 2) * 128;
    const int q0 = (swz & 3) * 64;

    // ---- B staging constants (unchanged from R13) ----
    const int rc  = tid >> 2;                                   // 0..63
    const int xkB = ((tid & 3) ^ ((tid >> 3) & 3)) * 8;
    const int stgB = (q0 + rc) * En + xkB;

    // ---- A f32 load/write constants: chunk c = j*256 + tid ----
    const int arow0 = tid >> 3;          // row within tile (+ j*32)
    const int ak8   = tid & 7;           // 16B chunk within 128B row
    const int axr   = (arow0 >> 1) & 3;  // XOR nibble (invariant to +j*32)
    const int aslot = arow0 * 32 + (((ak8 >> 1) ^ axr) * 8) + (ak8 & 1) * 4;

    // ---- fragment ds_read bases (frozen) ----
    const int xf  = (l >> 1) & 3;
    const int kx  = ((l >> 4) ^ xf) * 8;
    const int aFrag = (wm * 64 + (l & 15)) * 32 + kx;            // + m*512
    const int bFrag = 4096 + (wn * 32 + (l & 15)) * 32 + kx;     // + h*2048 + qs*512

    f32x4 acc[4][8];   // [m][f = h*2 + qsub]
    #pragma unroll
    for (int m = 0; m < 4; ++m)
        #pragma unroll
        for (int f = 0; f < 8; ++f) acc[m][f] = (f32x4){0.f, 0.f, 0.f, 0.f};

    float4 a4[4];
    auto issueA = [&](int t) {
        const int k0 = (t & 15) * 32;
        #pragma unroll
        for (int j = 0; j < 4; ++j)
            a4[j] = *(const float4*)(src + (size_t)(m0 + arow0 + j * 32) * En
                                     + k0 + ak8 * 4);
    };
    auto writeA = [&](int t) {
        const bool lo = (t >= 16) && (t < 32);
        f16* slotA = lds_f + (t % 3) * 12288;
        #pragma unroll
        for (int j = 0; j < 4; ++j) {
            const float xs[4] = {a4[j].x, a4[j].y, a4[j].z, a4[j].w};
            f16x4 hv;
            #pragma unroll
            for (int e = 0; e < 4; ++e) {
                f16 h = (f16)xs[e];
                hv[e] = lo ? (f16)(xs[e] - (float)h) : h;
            }
            *(f16x4*)(slotA + j * 1024 + aslot) = hv;
        }
    };
    auto stageB1 = [&](int t) {
        const f16* Bs = (t < 32) ? Bht : Blt;
        const int kofs = (t & 15) * 32;
        f16* dst = lds_f + (t % 3) * 12288 + 4096 + wv * 512;
        G2L(Bs + stgB + kofs,                dst);
        G2L(Bs + stgB + QD * En + kofs,      dst + 2048);
        G2L(Bs + stgB + 2 * QD * En + kofs,  dst + 4096);
        G2L(Bs + stgB + 3 * QD * En + kofs,  dst + 6144);
    };

    // prologue: A0 issued, B0+B1 staged; vmcnt(4) -> A0 returned, B0 landed
    issueA(0);
    stageB1(0);
    stageB1(1);
    VM4;
    writeA(0);
    LG0;
    __builtin_amdgcn_s_barrier();

    #pragma unroll
    for (int t = 0; t < 48; ++t) {
        if (t + 1 < 48) issueA(t + 1);     // A lead-1 (flat loads to regs)
        if (t + 2 < 48) stageB1(t + 2);    // B lead-2 (G2L)
        const f16* Lb = lds_f + (t % 3) * 12288;
        f16x8 af[4], bfr[8];
        #pragma unroll
        for (int m = 0; m < 4; ++m) af[m] = *(const f16x8*)(Lb + aFrag + m * 512);
        #pragma unroll
        for (int f = 0; f < 8; ++f)
            bfr[f] = *(const f16x8*)(Lb + bFrag + (f >> 1) * 2048 + (f & 1) * 512);
        __builtin_amdgcn_s_setprio(1);
        #pragma unroll
        for (int m = 0; m < 4; ++m) {
            #pragma unroll
            for (int f = 0; f < 8; ++f)
                acc[m][f] = __builtin_amdgcn_mfma_f32_16x16x32_f16(
                    af[m], bfr[f], acc[m][f], 0, 0, 0);
        }
        __builtin_amdgcn_s_setprio(0);
        if (t <= 45)      VM4;   // A(t+1) returned + B(t+1) landed; B(t+2) in flight
        else if (t == 46) VM0;   // drain: A(47) returned, all B landed
        if (t + 1 < 48) writeA(t + 1);   // cvt + ds_write into slot (t+1)%3
        LG0;                              // ds_writes + frag reads drained
        __builtin_amdgcn_s_barrier();
    }

    // epilogue: leaky_relu + head combine + hi/lo split store
    const float w0 = wcomb[0], w1 = wcomb[1], w2 = wcomb[2], w3 = wcomb[3];
    const int rbase = m0 + wm * 64 + (l >> 4) * 4;
    #pragma unroll
    for (int m = 0; m < 4; ++m) {
        #pragma unroll
        for (int qs = 0; qs < 2; ++qs) {
            const int q = q0 + wn * 32 + qs * 16 + (l & 15);
            #pragma unroll
            for (int i = 0; i < 4; ++i) {
                float x0 = acc[m][0 + qs][i]; x0 = x0 >= 0.f ? x0 : SLOPE * x0;
                float x1 = acc[m][2 + qs][i]; x1 = x1 >= 0.f ? x1 : SLOPE * x1;
                float x2 = acc[m][4 + qs][i]; x2 = x2 >= 0.f ? x2 : SLOPE * x2;
                float x3 = acc[m][6 + qs][i]; x3 = x3 >= 0.f ? x3 : SLOPE * x3;
                const float c = w0 * x0 + w1 * x1 + w2 * x2 + w3 * x3;
                const f16 ch = (f16)c;
                const f16 cl = (f16)(c - (float)ch);
                const size_t off = (size_t)(rbase + m * 16 + i) * QD + q;
                Ch[off] = ch;
                Cl[off] = cl;
            }
        }
    }
}

// ---------------------------------------------------------------------------
// K2: out[t,b,s] = dot(combined[b,s,:], query[t,b,:]) — R13 version, frozen.
//   XCD swizzle groups blocks by batch b; b's output rows land on XCD b>>1.
// ---------------------------------------------------------------------------
__global__ __launch_bounds__(256) void gemm2_kernel(
    const f16* __restrict__ Ch, const f16* __restrict__ Cl,
    const f16* __restrict__ Qh, const f16* __restrict__ Ql,
    const void* __restrict__ maskp, const float* __restrict__ wcomb,
    const int* __restrict__ flag,
    float* __restrict__ out)
{
    __shared__ f16 lds2[24576];   // 3 slots x (A 4096 + B 4096) f16

    const int tid = threadIdx.x;
    const int l  = tid & 63;
    const int wv = tid >> 6;
    const int wm = wv >> 1;          // s half
    const int wn = wv & 1;           // t half

    // XCD swizzle: 512 blocks; swz = [b(16)][s-tile(8)][t-tile(4)]
    const int bid = blockIdx.x;
    const int swz = (bid & 7) * 64 + (bid >> 3);
    const int b   = swz >> 5;
    const int s0  = ((swz >> 2) & 7) * 128;
    const int t0  = (swz & 3) * 128;

    const int rowc = tid >> 2;
    const int xk   = ((tid & 3) ^ ((rowc >> 1) & 3)) * 8;
    const int stgA = (b * Sn + s0 + rowc) * QD + xk;   // +64*QD instr2
    const int stgB = (b * Tn + t0 + rowc) * QD + xk;   // +64*QD instr2

    const int xf  = ((l >> 1) & 3);
    const int aFrag = (wm * 64 + (l & 15)) * 32 + (((l >> 4) ^ xf) * 8);
    const int bFrag = 4096 + (wn * 64 + (l & 15)) * 32 + (((l >> 4) ^ xf) * 8);

    f32x4 acc[4][4];
    #pragma unroll
    for (int m = 0; m < 4; ++m)
        #pragma unroll
        for (int n = 0; n < 4; ++n) acc[m][n] = (f32x4){0.f, 0.f, 0.f, 0.f};

    auto stage1 = [&](int t) {
        const f16* As = (t < 8) ? Ch : ((t < 16) ? Cl : Ch);
        const f16* Bs = (t < 16) ? Qh : Ql;
        const int kofs = (t & 7) * 32;
        f16* dst = lds2 + (t % 3) * 8192 + wv * 512;
        G2L(As + stgA + kofs,           dst);
        G2L(As + stgA + 64 * QD + kofs, dst + 2048);
        G2L(Bs + stgB + kofs,           dst + 4096);
        G2L(Bs + stgB + 64 * QD + kofs, dst + 4096 + 2048);
    };

    stage1(0);
    stage1(1);
    VM4;
    __builtin_amdgcn_s_barrier();

    #pragma unroll
    for (int kt = 0; kt < 24; ++kt) {
        if (kt + 2 < 24) stage1(kt + 2);
        const f16* Lb = lds2 + (kt % 3) * 8192;
        f16x8 af[4], bfr[4];
        #pragma unroll
        for (int m = 0; m < 4; ++m) af[m] = *(const f16x8*)(Lb + aFrag + m * 512);
        #pragma unroll
        for (int n = 0; n < 4; ++n) bfr[n] = *(const f16x8*)(Lb + bFrag + n * 512);
        __builtin_amdgcn_s_setprio(1);
        #pragma unroll
        for (int m = 0; m < 4; ++m) {
            #pragma unroll
            for (int n = 0; n < 4; ++n)
                acc[m][n] = __builtin_amdgcn_mfma_f32_16x16x32_f16(
                    af[m], bfr[n], acc[m][n], 0, 0, 0);
        }
        __builtin_amdgcn_s_setprio(0);
        if (kt <= 21)      VM4;
        else if (kt == 22) VM0;
        LG0;
        __builtin_amdgcn_s_barrier();
    }

    const float sumw = wcomb[0] + wcomb[1] + wcomb[2] + wcomb[3];
    const float maskval = NEG_INF * sumw;
    const bool is_int = (flag[0] != 0);
    const int rbase = s0 + wm * 64 + (l >> 4) * 4;

    bool msk[4][4];
    #pragma unroll
    for (int m = 0; m < 4; ++m)
        #pragma unroll
        for (int i = 0; i < 4; ++i) {
            const int idx = b * Sn + rbase + m * 16 + i;
            int mm;
            if (is_int) mm = ((const int*)maskp)[idx];
            else        mm = (int)((const unsigned char*)maskp)[idx];
            msk[m][i] = (mm != 0);
        }

    #pragma unroll
    for (int m = 0; m < 4; ++m)
        #pragma unroll
        for (int n = 0; n < 4; ++n) {
            const int t = t0 + wn * 64 + n * 16 + (l & 15);
            float vals[4];
            #pragma unroll
            for (int i = 0; i < 4; ++i)
                vals[i] = msk[m][i] ? maskval : acc[m][n][i];
            *(float4*)(out + ((size_t)t * Bn + b) * Sn + rbase + m * 16)
                = make_float4(vals[0], vals[1], vals[2], vals[3]);
        }
}

// ---------------------------------------------------------------------------
// K3: in-place softmax over last dim (S=1024). One block per (t,b) row.
//   XCD-affinity: row (t,b) runs on XCD b>>1 where gemm2 wrote its tiles.
// ---------------------------------------------------------------------------
__global__ __launch_bounds__(256) void softmax_kernel(float* __restrict__ out) {
    const int bid = blockIdx.x;
    const int k = bid & 7;           // XCD (round-robin dispatch)
    const int r = bid >> 3;          // 0..1023
    const int b = (k << 1) | (r & 1);
    const int t = r >> 1;
    const size_t row = (size_t)t * Bn + b;
    float* p = out + row * (size_t)Sn;
    const int tid = threadIdx.x;
    const int lane = tid & 63, wave = tid >> 6;

    float4 v = ((const float4*)p)[tid];

    float m = fmaxf(fmaxf(v.x, v.y), fmaxf(v.z, v.w));
    #pragma unroll
    for (int off = 32; off; off >>= 1) m = fmaxf(m, __shfl_down(m, off));
    __shared__ float smax[4];
    __shared__ float sm_all;
    if (lane == 0) smax[wave] = m;
    __syncthreads();
    if (tid == 0) sm_all = fmaxf(fmaxf(smax[0], smax[1]), fmaxf(smax[2], smax[3]));
    __syncthreads();
    m = sm_all;

    float e0 = __expf(v.x - m), e1 = __expf(v.y - m);
    float e2 = __expf(v.z - m), e3 = __expf(v.w - m);
    float s = e0 + e1 + e2 + e3;
    #pragma unroll
    for (int off = 32; off; off >>= 1) s += __shfl_down(s, off);
    __shared__ float ssum[4];
    __shared__ float ss_all;
    if (lane == 0) ssum[wave] = s;
    __syncthreads();
    if (tid == 0) ss_all = ssum[0] + ssum[1] + ssum[2] + ssum[3];
    __syncthreads();
    const float inv = 1.0f / ss_all;

    ((float4*)p)[tid] = make_float4(e0 * inv, e1 * inv, e2 * inv, e3 * inv);
}

// ---------------------------------------------------------------------------
extern "C" void kernel_launch(void* const* d_in, const int* in_sizes, int n_in,
                              void* d_out, int out_size, void* d_ws, size_t ws_size,
                              hipStream_t stream) {
    const float* src   = (const float*)d_in[0];  // (16,1024,512)
    const void*  maskp = d_in[1];                // (16,1024) bool/int32
    const float* query = (const float*)d_in[2];  // (512,16,256)
    const float* Wsrc  = (const float*)d_in[3];  // (512,1024)
    const float* wcomb = (const float*)d_in[4];  // (4,)
    float* out = (float*)d_out;                  // (512,16,1024)

    // workspace layout (26 MB + 256 B; no aliasing)
    constexpr size_t MB = 1024 * 1024;
    char* ws = (char*)d_ws;
    int* flag = (int*)ws;
    f16* Qh  = (f16*)(ws + 256);                 // 4 MB
    f16* Ql  = (f16*)(ws + 256 + 4 * MB);        // 4 MB
    f16* Bht = (f16*)(ws + 256 + 8 * MB);        // 1 MB
    f16* Blt = (f16*)(ws + 256 + 9 * MB);        // 1 MB
    f16* Ch  = (f16*)(ws + 256 + 10 * MB);       // 8 MB
    f16* Cl  = (f16*)(ws + 256 + 18 * MB);       // 8 MB

    prep_kernel<<<2177, 256, 0, stream>>>(
        Wsrc, query, (const unsigned char*)maskp, Bht, Blt, Qh, Ql, flag);

    gemm1_kernel<<<512, 256, 0, stream>>>(src, Bht, Blt, wcomb, Ch, Cl);

    gemm2_kernel<<<512, 256, 0, stream>>>(Ch, Cl, Qh, Ql, maskp, wcomb, flag, out);

    softmax_kernel<<<Tn * Bn, 256, 0, stream>>>(out);
}

// Round 16
// 108.161 us; speedup vs baseline: 1.0947x; 1.0947x over previous
//
#include <hip/hip_runtime.h>
#include <hip/hip_bf16.h>
#include <cstdint>

// Problem dims (fixed by reference setup_inputs)
constexpr int Bn = 16;    // batch
constexpr int Sn = 1024;  // source length
constexpr int Tn = 512;   // query steps
constexpr int QD = 256;   // query vec size
constexpr int En = 512;   // src encoding size
constexpr int Hn = 4;     // heads
constexpr float SLOPE = 0.01f;   // jax.nn.leaky_relu default
constexpr float NEG_INF = -1e9f;
constexpr int Mn = Bn * Sn;      // 16384 rows of the projection GEMM

typedef _Float16 f16;
typedef f16 f16x4 __attribute__((ext_vector_type(4)));
typedef f16 f16x8 __attribute__((ext_vector_type(8)));
typedef float f32x4 __attribute__((ext_vector_type(4)));

// async global->LDS, 16B per lane; dest = wave-uniform base + lane*16
#define G2L(g, l) __builtin_amdgcn_global_load_lds(                      \
    (const __attribute__((address_space(1))) void*)(g),                  \
    (__attribute__((address_space(3))) void*)(l), 16, 0, 0)

#define VM6 asm volatile("s_waitcnt vmcnt(6)" ::: "memory")
#define VM4 asm volatile("s_waitcnt vmcnt(4)" ::: "memory")
#define VM0 asm volatile("s_waitcnt vmcnt(0)" ::: "memory")
#define LG0 asm volatile("s_waitcnt lgkmcnt(0)" ::: "memory")

// ---------------------------------------------------------------------------
// Device helpers shared by prep variants
// ---------------------------------------------------------------------------
__device__ __forceinline__ void do_conv_a(const float* __restrict__ src,
                                          f16* __restrict__ Ah, f16* __restrict__ Al,
                                          int bid, int tid) {
    const size_t i4 = (size_t)bid * 256 + tid;
    const size_t base = i4 * 4;
    const float4 v = *(const float4*)(src + base);
    f16x4 hi, lo;
    const float xs[4] = {v.x, v.y, v.z, v.w};
    #pragma unroll
    for (int j = 0; j < 4; ++j) {
        f16 h = (f16)xs[j];
        hi[j] = h;
        lo[j] = (f16)(xs[j] - (float)h);
    }
    *(f16x4*)(Ah + base) = hi;
    *(f16x4*)(Al + base) = lo;
}

__device__ __forceinline__ void do_conv_b(const float* __restrict__ W,
                                          f16* __restrict__ Bht, f16* __restrict__ Blt,
                                          float (*T)[65], int nb, int tid) {
    const int n0 = (nb & 15) * 64;
    const int k0 = (nb >> 4) * 64;
    #pragma unroll
    for (int p = 0; p < 4; ++p) {
        const int e = p * 256 + tid;
        const int r = e >> 4;
        const int c4 = e & 15;
        const float4 v = *(const float4*)(W + (size_t)(k0 + r) * (Hn * QD) + n0 + c4 * 4);
        T[r][c4 * 4 + 0] = v.x; T[r][c4 * 4 + 1] = v.y;
        T[r][c4 * 4 + 2] = v.z; T[r][c4 * 4 + 3] = v.w;
    }
    __syncthreads();
    #pragma unroll
    for (int p = 0; p < 4; ++p) {
        const int e = p * 256 + tid;
        const int r = e >> 4;
        const int c4 = e & 15;
        f16x4 hi, lo;
        #pragma unroll
        for (int j = 0; j < 4; ++j) {
            const float x = T[c4 * 4 + j][r];
            f16 h = (f16)x;
            hi[j] = h;
            lo[j] = (f16)(x - (float)h);
        }
        const size_t off = (size_t)(n0 + r) * En + k0 + c4 * 4;
        *(f16x4*)(Bht + off) = hi;
        *(f16x4*)(Blt + off) = lo;
    }
}

__device__ __forceinline__ void do_conv_q(const float* __restrict__ query,
                                          f16* __restrict__ Qh, f16* __restrict__ Ql,
                                          int qb, int tid) {
    const int rloc = tid >> 6;
    const int lane = tid & 63;
    const int row = qb * 4 + rloc;   // (t,b) pair, t-major
    const int t = row >> 4, b = row & 15;
    const float4 v = *(const float4*)(query + (size_t)row * QD + lane * 4);
    f16x4 hi, lo;
    const float xs[4] = {v.x, v.y, v.z, v.w};
    #pragma unroll
    for (int j = 0; j < 4; ++j) {
        f16 h = (f16)xs[j];
        hi[j] = h;
        lo[j] = (f16)(xs[j] - (float)h);
    }
    const size_t off = ((size_t)(b * Tn + t)) * QD + lane * 4;
    *(f16x4*)(Qh + off) = hi;
    *(f16x4*)(Ql + off) = lo;
}

__device__ __forceinline__ void do_detect(const unsigned char* __restrict__ mask_bytes,
                                          int* __restrict__ flag,
                                          int* cnt, int tid) {
    if (tid == 0) *cnt = 0;
    __syncthreads();
    int local = 0;
    for (int p = tid; p < 4096; p += 256) {
        if ((p & 3) != 0 && mask_bytes[p] != 0) local++;
    }
    atomicAdd(cnt, local);
    __syncthreads();
    if (tid == 0) flag[0] = (*cnt == 0) ? 1 : 0;
}

// ---------------------------------------------------------------------------
// PREP (fused-all, 10369 blocks): conv_a 0..8191, conv_b 8192..8319,
//   conv_q 8320..10367, detect 10368. Used when ws fits non-aliased layout.
// ---------------------------------------------------------------------------
__global__ __launch_bounds__(256) void prep_all_kernel(
    const float* __restrict__ src, const float* __restrict__ W,
    const float* __restrict__ query,
    const unsigned char* __restrict__ mask_bytes,
    f16* __restrict__ Ah, f16* __restrict__ Al,
    f16* __restrict__ Bht, f16* __restrict__ Blt,
    f16* __restrict__ Qh, f16* __restrict__ Ql,
    int* __restrict__ flag)
{
    __shared__ float T[64][65];
    __shared__ int cnt;
    const int bid = blockIdx.x;
    const int tid = threadIdx.x;
    if (bid < 8192)       do_conv_a(src, Ah, Al, bid, tid);
    else if (bid < 8320)  do_conv_b(W, Bht, Blt, T, bid - 8192, tid);
    else if (bid < 10368) do_conv_q(query, Qh, Ql, bid - 8320, tid);
    else                  do_detect(mask_bytes, flag, &cnt, tid);
}

// ---------------------------------------------------------------------------
// PREP (R14 fallback, 8321 blocks): conv_a + conv_b + detect. conv_q runs
//   separately after gemm1 (Qh/Ql alias the Ah region).
// ---------------------------------------------------------------------------
__global__ __launch_bounds__(256) void prep_kernel(
    const float* __restrict__ src, const float* __restrict__ W,
    const unsigned char* __restrict__ mask_bytes,
    f16* __restrict__ Ah, f16* __restrict__ Al,
    f16* __restrict__ Bht, f16* __restrict__ Blt,
    int* __restrict__ flag)
{
    __shared__ float T[64][65];
    __shared__ int cnt;
    const int bid = blockIdx.x;
    const int tid = threadIdx.x;
    if (bid < 8192)      do_conv_a(src, Ah, Al, bid, tid);
    else if (bid < 8320) do_conv_b(W, Bht, Blt, T, bid - 8192, tid);
    else                 do_detect(mask_bytes, flag, &cnt, tid);
}

__global__ __launch_bounds__(256) void conv_q_kernel(
    const float* __restrict__ query, f16* __restrict__ Qh, f16* __restrict__ Ql)
{
    do_conv_q(query, Qh, Ql, blockIdx.x, threadIdx.x);
}

// ---------------------------------------------------------------------------
// K1: 128(rows) x 256(cols = 64q x 4heads) tile, BK=32, ring-3, lead-2.
//   R13/R14 version, FROZEN (59.6 us, MfmaUtil ~34% = structure-class
//   ceiling; fetch-bound and reg-staging theories falsified R13/R15).
//   XCD-aware swizzle: same-A quads co-XCD.
// ---------------------------------------------------------------------------
__global__ __launch_bounds__(256) void gemm1_kernel(
    const f16* __restrict__ Ah, const f16* __restrict__ Al,
    const f16* __restrict__ Bht, const f16* __restrict__ Blt,
    const float* __restrict__ wcomb,
    f16* __restrict__ Ch, f16* __restrict__ Cl)
{
    __shared__ f16 lds_f[36864];   // 3 slots x 12288 f16 = 72 KB

    const int tid = threadIdx.x;
    const int l  = tid & 63;
    const int wv = tid >> 6;         // 0..3
    const int wm = wv >> 1;          // M half (64 rows)
    const int wn = wv & 1;           // q half (32 q)

    // XCD swizzle: 512 blocks, 8 XCDs, 64 per XCD; same-A quads co-XCD
    const int bid = blockIdx.x;
    const int swz = (bid & 7) * 64 + (bid >> 3);
    const int m0 = (swz >> 2) * 128;
    const int q0 = (swz & 3) * 64;

    // staging constants: chunk c = i*256 + tid; row/col = c>>2, k4 = c&3
    const int rc  = tid >> 2;                                   // 0..63
    const int xk  = ((tid & 3) ^ ((tid >> 3) & 3)) * 8;         // XOR'd k-chunk
    const int stgA = (m0 + rc) * En + xk;        // A rows rc, rc+64
    const int stgB = (q0 + rc) * En + xk;        // B strips: +i*QD*En per head

    // fragment ds_read bases (f16 idx); xor nibble lane-constant
    const int xf  = (l >> 1) & 3;
    const int kx  = ((l >> 4) ^ xf) * 8;
    const int aFrag = (wm * 64 + (l & 15)) * 32 + kx;            // + m*512
    const int bFrag = 4096 + (wn * 32 + (l & 15)) * 32 + kx;     // + h*2048 + qs*512

    f32x4 acc[4][8];   // [m][f = h*2 + qsub]
    #pragma unroll
    for (int m = 0; m < 4; ++m)
        #pragma unroll
        for (int f = 0; f < 8; ++f) acc[m][f] = (f32x4){0.f, 0.f, 0.f, 0.f};

    auto stage1 = [&](int t) {
        const f16* As = (t < 16) ? Ah : ((t < 32) ? Al : Ah);
        const f16* Bs = (t < 32) ? Bht : Blt;
        const int kofs = (t & 15) * 32;
        f16* dst = lds_f + (t % 3) * 12288 + wv * 512;
        G2L(As + stgA + kofs,                dst);
        G2L(As + stgA + 64 * En + kofs,      dst + 2048);
        G2L(Bs + stgB + kofs,                dst + 4096);
        G2L(Bs + stgB + QD * En + kofs,      dst + 4096 + 2048);
        G2L(Bs + stgB + 2 * QD * En + kofs,  dst + 4096 + 4096);
        G2L(Bs + stgB + 3 * QD * En + kofs,  dst + 4096 + 6144);
    };

    // prologue: tiles 0,1 staged; wait tile0 (6 of tile1 outstanding)
    stage1(0);
    stage1(1);
    VM6;
    __builtin_amdgcn_s_barrier();

    #pragma unroll
    for (int t = 0; t < 48; ++t) {
        if (t + 2 < 48) stage1(t + 2);   // issue next-next tile first
        const f16* Lb = lds_f + (t % 3) * 12288;
        f16x8 af[4], bfr[8];
        #pragma unroll
        for (int m = 0; m < 4; ++m) af[m] = *(const f16x8*)(Lb + aFrag + m * 512);
        #pragma unroll
        for (int f = 0; f < 8; ++f)
            bfr[f] = *(const f16x8*)(Lb + bFrag + (f >> 1) * 2048 + (f & 1) * 512);
        __builtin_amdgcn_s_setprio(1);
        #pragma unroll
        for (int m = 0; m < 4; ++m) {
            #pragma unroll
            for (int f = 0; f < 8; ++f)
                acc[m][f] = __builtin_amdgcn_mfma_f32_16x16x32_f16(
                    af[m], bfr[f], acc[m][f], 0, 0, 0);
        }
        __builtin_amdgcn_s_setprio(0);
        if (t <= 45)      VM6;   // tile t+1 landed (tile t+2's 6 remain)
        else if (t == 46) VM0;   // drain: tile 47 landed
        LG0;                      // trivially satisfied; pins WAR for slot reuse
        __builtin_amdgcn_s_barrier();
    }

    // epilogue: leaky_relu + head combine + hi/lo split store
    const float w0 = wcomb[0], w1 = wcomb[1], w2 = wcomb[2], w3 = wcomb[3];
    const int rbase = m0 + wm * 64 + (l >> 4) * 4;
    #pragma unroll
    for (int m = 0; m < 4; ++m) {
        #pragma unroll
        for (int qs = 0; qs < 2; ++qs) {
            const int q = q0 + wn * 32 + qs * 16 + (l & 15);
            #pragma unroll
            for (int i = 0; i < 4; ++i) {
                float x0 = acc[m][0 + qs][i]; x0 = x0 >= 0.f ? x0 : SLOPE * x0;
                float x1 = acc[m][2 + qs][i]; x1 = x1 >= 0.f ? x1 : SLOPE * x1;
                float x2 = acc[m][4 + qs][i]; x2 = x2 >= 0.f ? x2 : SLOPE * x2;
                float x3 = acc[m][6 + qs][i]; x3 = x3 >= 0.f ? x3 : SLOPE * x3;
                const float c = w0 * x0 + w1 * x1 + w2 * x2 + w3 * x3;
                const f16 ch = (f16)c;
                const f16 cl = (f16)(c - (float)ch);
                const size_t off = (size_t)(rbase + m * 16 + i) * QD + q;
                Ch[off] = ch;
                Cl[off] = cl;
            }
        }
    }
}

// ---------------------------------------------------------------------------
// K2: out[t,b,s] = dot(combined[b,s,:], query[t,b,:]) — R13/R14 version,
//   FROZEN. XCD swizzle groups blocks by batch b; b's output rows land on
//   XCD b>>1 (softmax exploits this).
// ---------------------------------------------------------------------------
__global__ __launch_bounds__(256) void gemm2_kernel(
    const f16* __restrict__ Ch, const f16* __restrict__ Cl,
    const f16* __restrict__ Qh, const f16* __restrict__ Ql,
    const void* __restrict__ maskp, const float* __restrict__ wcomb,
    const int* __restrict__ flag,
    float* __restrict__ out)
{
    __shared__ f16 lds2[24576];   // 3 slots x (A 4096 + B 4096) f16

    const int tid = threadIdx.x;
    const int l  = tid & 63;
    const int wv = tid >> 6;
    const int wm = wv >> 1;          // s half
    const int wn = wv & 1;           // t half

    // XCD swizzle: 512 blocks; swz = [b(16)][s-tile(8)][t-tile(4)]
    const int bid = blockIdx.x;
    const int swz = (bid & 7) * 64 + (bid >> 3);
    const int b   = swz >> 5;
    const int s0  = ((swz >> 2) & 7) * 128;
    const int t0  = (swz & 3) * 128;

    const int rowc = tid >> 2;
    const int xk   = ((tid & 3) ^ ((rowc >> 1) & 3)) * 8;
    const int stgA = (b * Sn + s0 + rowc) * QD + xk;   // +64*QD instr2
    const int stgB = (b * Tn + t0 + rowc) * QD + xk;   // +64*QD instr2

    const int xf  = ((l >> 1) & 3);
    const int aFrag = (wm * 64 + (l & 15)) * 32 + (((l >> 4) ^ xf) * 8);
    const int bFrag = 4096 + (wn * 64 + (l & 15)) * 32 + (((l >> 4) ^ xf) * 8);

    f32x4 acc[4][4];
    #pragma unroll
    for (int m = 0; m < 4; ++m)
        #pragma unroll
        for (int n = 0; n < 4; ++n) acc[m][n] = (f32x4){0.f, 0.f, 0.f, 0.f};

    auto stage1 = [&](int t) {
        const f16* As = (t < 8) ? Ch : ((t < 16) ? Cl : Ch);
        const f16* Bs = (t < 16) ? Qh : Ql;
        const int kofs = (t & 7) * 32;
        f16* dst = lds2 + (t % 3) * 8192 + wv * 512;
        G2L(As + stgA + kofs,           dst);
        G2L(As + stgA + 64 * QD + kofs, dst + 2048);
        G2L(Bs + stgB + kofs,           dst + 4096);
        G2L(Bs + stgB + 64 * QD + kofs, dst + 4096 + 2048);
    };

    stage1(0);
    stage1(1);
    VM4;
    __builtin_amdgcn_s_barrier();

    #pragma unroll
    for (int kt = 0; kt < 24; ++kt) {
        if (kt + 2 < 24) stage1(kt + 2);
        const f16* Lb = lds2 + (kt % 3) * 8192;
        f16x8 af[4], bfr[4];
        #pragma unroll
        for (int m = 0; m < 4; ++m) af[m] = *(const f16x8*)(Lb + aFrag + m * 512);
        #pragma unroll
        for (int n = 0; n < 4; ++n) bfr[n] = *(const f16x8*)(Lb + bFrag + n * 512);
        __builtin_amdgcn_s_setprio(1);
        #pragma unroll
        for (int m = 0; m < 4; ++m) {
            #pragma unroll
            for (int n = 0; n < 4; ++n)
                acc[m][n] = __builtin_amdgcn_mfma_f32_16x16x32_f16(
                    af[m], bfr[n], acc[m][n], 0, 0, 0);
        }
        __builtin_amdgcn_s_setprio(0);
        if (kt <= 21)      VM4;
        else if (kt == 22) VM0;
        LG0;
        __builtin_amdgcn_s_barrier();
    }

    const float sumw = wcomb[0] + wcomb[1] + wcomb[2] + wcomb[3];
    const float maskval = NEG_INF * sumw;
    const bool is_int = (flag[0] != 0);
    const int rbase = s0 + wm * 64 + (l >> 4) * 4;

    bool msk[4][4];
    #pragma unroll
    for (int m = 0; m < 4; ++m)
        #pragma unroll
        for (int i = 0; i < 4; ++i) {
            const int idx = b * Sn + rbase + m * 16 + i;
            int mm;
            if (is_int) mm = ((const int*)maskp)[idx];
            else        mm = (int)((const unsigned char*)maskp)[idx];
            msk[m][i] = (mm != 0);
        }

    #pragma unroll
    for (int m = 0; m < 4; ++m)
        #pragma unroll
        for (int n = 0; n < 4; ++n) {
            const int t = t0 + wn * 64 + n * 16 + (l & 15);
            float vals[4];
            #pragma unroll
            for (int i = 0; i < 4; ++i)
                vals[i] = msk[m][i] ? maskval : acc[m][n][i];
            *(float4*)(out + ((size_t)t * Bn + b) * Sn + rbase + m * 16)
                = make_float4(vals[0], vals[1], vals[2], vals[3]);
        }
}

// ---------------------------------------------------------------------------
// K3: in-place softmax over last dim (S=1024). One block per (t,b) row.
//   XCD-affinity: row (t,b) runs on XCD b>>1 where gemm2 wrote its tiles.
// ---------------------------------------------------------------------------
__global__ __launch_bounds__(256) void softmax_kernel(float* __restrict__ out) {
    const int bid = blockIdx.x;
    const int k = bid & 7;           // XCD (round-robin dispatch)
    const int r = bid >> 3;          // 0..1023
    const int b = (k << 1) | (r & 1);
    const int t = r >> 1;
    const size_t row = (size_t)t * Bn + b;
    float* p = out + row * (size_t)Sn;
    const int tid = threadIdx.x;
    const int lane = tid & 63, wave = tid >> 6;

    float4 v = ((const float4*)p)[tid];

    float m = fmaxf(fmaxf(v.x, v.y), fmaxf(v.z, v.w));
    #pragma unroll
    for (int off = 32; off; off >>= 1) m = fmaxf(m, __shfl_down(m, off));
    __shared__ float smax[4];
    __shared__ float sm_all;
    if (lane == 0) smax[wave] = m;
    __syncthreads();
    if (tid == 0) sm_all = fmaxf(fmaxf(smax[0], smax[1]), fmaxf(smax[2], smax[3]));
    __syncthreads();
    m = sm_all;

    float e0 = __expf(v.x - m), e1 = __expf(v.y - m);
    float e2 = __expf(v.z - m), e3 = __expf(v.w - m);
    float s = e0 + e1 + e2 + e3;
    #pragma unroll
    for (int off = 32; off; off >>= 1) s += __shfl_down(s, off);
    __shared__ float ssum[4];
    __shared__ float ss_all;
    if (lane == 0) ssum[wave] = s;
    __syncthreads();
    if (tid == 0) ss_all = ssum[0] + ssum[1] + ssum[2] + ssum[3];
    __syncthreads();
    const float inv = 1.0f / ss_all;

    ((float4*)p)[tid] = make_float4(e0 * inv, e1 * inv, e2 * inv, e3 * inv);
}

// ---------------------------------------------------------------------------
extern "C" void kernel_launch(void* const* d_in, const int* in_sizes, int n_in,
                              void* d_out, int out_size, void* d_ws, size_t ws_size,
                              hipStream_t stream) {
    const float* src   = (const float*)d_in[0];  // (16,1024,512)
    const void*  maskp = d_in[1];                // (16,1024) bool/int32
    const float* query = (const float*)d_in[2];  // (512,16,256)
    const float* Wsrc  = (const float*)d_in[3];  // (512,1024)
    const float* wcomb = (const float*)d_in[4];  // (4,)
    float* out = (float*)d_out;                  // (512,16,1024)

    constexpr size_t MB = 1024 * 1024;
    char* ws = (char*)d_ws;
    int* flag = (int*)ws;
    f16* Ah  = (f16*)(ws + 256);                  // 16 MB
    f16* Al  = (f16*)(ws + 256 + 16 * MB);        // 16 MB
    f16* Bht = (f16*)(ws + 256 + 32 * MB);        // 1 MB
    f16* Blt = (f16*)(ws + 256 + 33 * MB);        // 1 MB
    f16* Ch  = (f16*)(ws + 256 + 34 * MB);        // 8 MB
    f16* Cl  = (f16*)(ws + 256 + 42 * MB);        // 8 MB

    const bool big_ws = (ws_size >= 58 * MB + 256);

    if (big_ws) {
        // non-aliased Qh/Ql -> conv_q can run inside prep (4 launches)
        f16* Qh = (f16*)(ws + 256 + 50 * MB);     // 4 MB
        f16* Ql = (f16*)(ws + 256 + 54 * MB);     // 4 MB
        prep_all_kernel<<<10369, 256, 0, stream>>>(
            src, Wsrc, query, (const unsigned char*)maskp,
            Ah, Al, Bht, Blt, Qh, Ql, flag);
        gemm1_kernel<<<512, 256, 0, stream>>>(Ah, Al, Bht, Blt, wcomb, Ch, Cl);
        gemm2_kernel<<<512, 256, 0, stream>>>(Ch, Cl, Qh, Ql, maskp, wcomb, flag, out);
        softmax_kernel<<<Tn * Bn, 256, 0, stream>>>(out);
    } else {
        // R14 fallback: Qh/Ql alias Ah (free after gemm1); 5 launches
        f16* Qh = (f16*)(ws + 256);
        f16* Ql = (f16*)(ws + 256 + 4 * MB);
        prep_kernel<<<8321, 256, 0, stream>>>(
            src, Wsrc, (const unsigned char*)maskp, Ah, Al, Bht, Blt, flag);
        gemm1_kernel<<<512, 256, 0, stream>>>(Ah, Al, Bht, Blt, wcomb, Ch, Cl);
        conv_q_kernel<<<(Tn * Bn) / 4, 256, 0, stream>>>(query, Qh, Ql);
        gemm2_kernel<<<512, 256, 0, stream>>>(Ch, Cl, Qh, Ql, maskp, wcomb, flag, out);
        softmax_kernel<<<Tn * Bn, 256, 0, stream>>>(out);
    }
}